// Round 1
// baseline (1245.556 us; speedup 1.0000x reference)
//
#include <hip/hip_runtime.h>
#include <stdint.h>

#define NH 16
#define NKV 4
#define HD 128
#define QS (NH*HD)     /* 2048 */
#define KSR (NKV*HD)   /* 512  */
#define SCALE 0.08838834764831845f

typedef float f32x4 __attribute__((ext_vector_type(4)));
typedef __bf16 bf16x8 __attribute__((ext_vector_type(8)));

// ---------------------------------------------------------------------------
// Attention: one 64-lane wave per (head, q-block of 32 rows).
// Staircase mask => q-block qb attends keys [0, (qb+1)*32) with NO masking.
// ---------------------------------------------------------------------------
__global__ __launch_bounds__(64) void attn_kernel(
    const float* __restrict__ q, const float* __restrict__ k,
    const float* __restrict__ v, float* __restrict__ o, int nqb) {
  __shared__ __bf16 Kt[32][128];  // K tile, col-chunk XOR-swizzled by (row&7)
  __shared__ __bf16 VT[128][32];  // V tile transposed [d][key], swizzled by (d>>2)&3
  __shared__ __bf16 Pt[32][32];   // P transpose buffer, swizzled by (row>>2)&3

  const int lane = threadIdx.x;
  const int g = lane >> 4, r = lane & 15;
  const int h = blockIdx.x & (NH - 1);
  const int qb = (nqb - 1) - (blockIdx.x >> 4);  // longest blocks first
  const int kvh = h >> 2;

  // ---- Q fragments (A-operand): Q[16*mt + r][32*ks + 8*g + j] ----
  bf16x8 qf[2][4];
#pragma unroll
  for (int mt = 0; mt < 2; ++mt) {
#pragma unroll
    for (int ks = 0; ks < 4; ++ks) {
      const float* src = q + (size_t)(qb * 32 + 16 * mt + r) * QS + h * HD + 32 * ks + 8 * g;
      f32x4 a = *(const f32x4*)src;
      f32x4 b = *(const f32x4*)(src + 4);
      bf16x8 t;
      t[0] = (__bf16)a[0]; t[1] = (__bf16)a[1]; t[2] = (__bf16)a[2]; t[3] = (__bf16)a[3];
      t[4] = (__bf16)b[0]; t[5] = (__bf16)b[1]; t[6] = (__bf16)b[2]; t[7] = (__bf16)b[3];
      qf[mt][ks] = t;
    }
  }

  f32x4 oacc[2][8];
#pragma unroll
  for (int mt = 0; mt < 2; ++mt)
#pragma unroll
    for (int nt = 0; nt < 8; ++nt) oacc[mt][nt] = (f32x4){0.f, 0.f, 0.f, 0.f};

  float mrun[2][4], lrun[2][4];
#pragma unroll
  for (int mt = 0; mt < 2; ++mt)
#pragma unroll
    for (int j = 0; j < 4; ++j) { mrun[mt][j] = -1e30f; lrun[mt][j] = 0.f; }

  const int vkey = lane & 31, vdh = lane >> 5;

  for (int kt = 0; kt <= qb; ++kt) {
    __syncthreads();  // protect LDS vs previous iteration's reads

    // ---- stage K tile: 32 keys x 128 dims, fp32 -> bf16 ----
#pragma unroll
    for (int i = 0; i < 8; ++i) {
      int chunk = i * 64 + lane;        // 512 chunks of 8 dims
      int row = chunk >> 4;             // key within tile
      int col = (chunk & 15) << 3;      // dim base
      const float* src = k + (size_t)(kt * 32 + row) * KSR + kvh * HD + col;
      f32x4 a = *(const f32x4*)src;
      f32x4 b = *(const f32x4*)(src + 4);
      bf16x8 t;
      t[0] = (__bf16)a[0]; t[1] = (__bf16)a[1]; t[2] = (__bf16)a[2]; t[3] = (__bf16)a[3];
      t[4] = (__bf16)b[0]; t[5] = (__bf16)b[1]; t[6] = (__bf16)b[2]; t[7] = (__bf16)b[3];
      *(bf16x8*)&Kt[row][col ^ ((row & 7) << 3)] = t;
    }

    // ---- stage V tile transposed: VT[d][key] ----
#pragma unroll
    for (int i = 0; i < 16; ++i) {
      int d0 = i * 8 + vdh * 4;
      f32x4 a = *(const f32x4*)(v + (size_t)(kt * 32 + vkey) * KSR + kvh * HD + d0);
#pragma unroll
      for (int qq = 0; qq < 4; ++qq) {
        int d = d0 + qq;
        VT[d][vkey ^ (((d >> 2) & 3) << 3)] = (__bf16)a[qq];
      }
    }
    __syncthreads();

    // ---- S = Q K^T (32x32, K-dim 128) ----
    f32x4 sacc[2][2];
#pragma unroll
    for (int mt = 0; mt < 2; ++mt) {
#pragma unroll
      for (int nt2 = 0; nt2 < 2; ++nt2) {
        f32x4 c = (f32x4){0.f, 0.f, 0.f, 0.f};
#pragma unroll
        for (int ks = 0; ks < 4; ++ks) {
          int row = 16 * nt2 + r;  // key index (B-operand n = lane&15)
          bf16x8 kf = *(const bf16x8*)&Kt[row][(32 * ks + 8 * g) ^ ((row & 7) << 3)];
          c = __builtin_amdgcn_mfma_f32_16x16x32_bf16(qf[mt][ks], kf, c, 0, 0, 0);
        }
        sacc[mt][nt2] = c;
      }
    }

    // ---- online softmax: row stats per (mt, reg), 16-lane group reduce ----
#pragma unroll
    for (int mt = 0; mt < 2; ++mt) {
#pragma unroll
      for (int j = 0; j < 4; ++j) {
        float s0 = sacc[mt][0][j] * SCALE, s1 = sacc[mt][1][j] * SCALE;
        float mx = fmaxf(s0, s1);
        mx = fmaxf(mx, __shfl_xor(mx, 1));
        mx = fmaxf(mx, __shfl_xor(mx, 2));
        mx = fmaxf(mx, __shfl_xor(mx, 4));
        mx = fmaxf(mx, __shfl_xor(mx, 8));
        float mnew = fmaxf(mrun[mt][j], mx);
        float cf = __expf(mrun[mt][j] - mnew);
        mrun[mt][j] = mnew;
        float p0 = __expf(s0 - mnew), p1 = __expf(s1 - mnew);
        sacc[mt][0][j] = p0; sacc[mt][1][j] = p1;
        float ts = p0 + p1;
        ts += __shfl_xor(ts, 1);
        ts += __shfl_xor(ts, 2);
        ts += __shfl_xor(ts, 4);
        ts += __shfl_xor(ts, 8);
        lrun[mt][j] = lrun[mt][j] * cf + ts;
#pragma unroll
        for (int nt = 0; nt < 8; ++nt) oacc[mt][nt][j] *= cf;
      }
    }

    // ---- P -> LDS (transpose to A-operand layout) ----
#pragma unroll
    for (int mt = 0; mt < 2; ++mt) {
#pragma unroll
      for (int nt2 = 0; nt2 < 2; ++nt2) {
#pragma unroll
        for (int j = 0; j < 4; ++j) {
          int row = 16 * mt + 4 * g + j;
          int col = (16 * nt2 + r) ^ (((row >> 2) & 3) << 3);
          Pt[row][col] = (__bf16)sacc[mt][nt2][j];
        }
      }
    }
    __syncthreads();

    // ---- O += P V ----
#pragma unroll
    for (int mt = 0; mt < 2; ++mt) {
      int prow = 16 * mt + r;
      bf16x8 pf = *(const bf16x8*)&Pt[prow][(8 * g) ^ (((prow >> 2) & 3) << 3)];
#pragma unroll
      for (int nt = 0; nt < 8; ++nt) {
        int dd = 16 * nt + r;
        bf16x8 vf = *(const bf16x8*)&VT[dd][(8 * g) ^ (((dd >> 2) & 3) << 3)];
        oacc[mt][nt] = __builtin_amdgcn_mfma_f32_16x16x32_bf16(pf, vf, oacc[mt][nt], 0, 0, 0);
      }
    }
  }

  // ---- epilogue: normalize and store ----
#pragma unroll
  for (int mt = 0; mt < 2; ++mt) {
#pragma unroll
    for (int j = 0; j < 4; ++j) {
      float inv = 1.0f / lrun[mt][j];
      int row = qb * 32 + 16 * mt + 4 * g + j;
#pragma unroll
      for (int nt = 0; nt < 8; ++nt)
        o[(size_t)row * QS + h * HD + 16 * nt + r] = oacc[mt][nt][j] * inv;
    }
  }
}

// ---------------------------------------------------------------------------
// Cache copy then scatter (ordered on stream)
// ---------------------------------------------------------------------------
__global__ void copy_caches_kernel(const f32x4* __restrict__ kc, const f32x4* __restrict__ vc,
                                   f32x4* __restrict__ okc, f32x4* __restrict__ ovc, int n4) {
  int i = blockIdx.x * blockDim.x + threadIdx.x;
  int stride = gridDim.x * blockDim.x;
  for (; i < n4; i += stride) {
    okc[i] = kc[i];
    ovc[i] = vc[i];
  }
}

__global__ void scatter_kernel(const float* __restrict__ k, const float* __restrict__ v,
                               const int* __restrict__ slot, float* __restrict__ okc,
                               float* __restrict__ ovc, int t) {
  int i = blockIdx.x * blockDim.x + threadIdx.x;
  int row = i >> 7, c = i & 127;  // 128 float4 per 512-float row
  if (row < t) {
    int s = slot[row];
    ((f32x4*)okc)[(size_t)s * 128 + c] = ((const f32x4*)k)[(size_t)row * 128 + c];
    ((f32x4*)ovc)[(size_t)s * 128 + c] = ((const f32x4*)v)[(size_t)row * 128 + c];
  }
}

extern "C" void kernel_launch(void* const* d_in, const int* in_sizes, int n_in,
                              void* d_out, int out_size, void* d_ws, size_t ws_size,
                              hipStream_t stream) {
  const float* q = (const float*)d_in[0];
  const float* k = (const float*)d_in[1];
  const float* v = (const float*)d_in[2];
  const float* kc = (const float*)d_in[3];
  const float* vc = (const float*)d_in[4];
  const int* slot = (const int*)d_in[5];

  const int t = in_sizes[0] / QS;           // 4096
  const int nslots = in_sizes[3] / KSR;     // 8192
  const int nqb = t / 32;                   // 128

  float* o = (float*)d_out;
  float* okc = o + (size_t)t * QS;
  float* ovc = okc + (size_t)nslots * KSR;

  hipLaunchKernelGGL(attn_kernel, dim3(nqb * NH), dim3(64), 0, stream, q, k, v, o, nqb);

  int n4 = nslots * KSR / 4;
  hipLaunchKernelGGL(copy_caches_kernel, dim3(2048), dim3(256), 0, stream,
                     (const f32x4*)kc, (const f32x4*)vc, (f32x4*)okc, (f32x4*)ovc, n4);

  int nthreads = t * (KSR / 4);
  hipLaunchKernelGGL(scatter_kernel, dim3((nthreads + 255) / 256), dim3(256), 0, stream,
                     k, v, slot, okc, ovc, t);
}

// Round 2
// 387.994 us; speedup vs baseline: 3.2102x; 3.2102x over previous
//
#include <hip/hip_runtime.h>
#include <stdint.h>
#include <type_traits>

#define NH 16
#define NKV 4
#define HD 128
#define QS (NH*HD)     /* 2048 */
#define KSR (NKV*HD)   /* 512  */
#define SCALE 0.08838834764831845f

typedef float f32x4 __attribute__((ext_vector_type(4)));
typedef __bf16 bf16x8 __attribute__((ext_vector_type(8)));
typedef __bf16 bf16x4 __attribute__((ext_vector_type(4)));
typedef __bf16 bf16x2 __attribute__((ext_vector_type(2)));

// ---------------------------------------------------------------------------
// 4 waves x 32 Q-rows = 128-row macro tile per block; KVBLK=64, double-buffered
// LDS, swapped QK^T (in-register softmax), one barrier per tile.
// Staircase: q-block qb attends exactly (qb+1)*32 keys -> tile-granular, no
// element masking (NG = 4 full / 2 half 16-key groups, compile-time).
// ---------------------------------------------------------------------------
__global__ __launch_bounds__(256, 2) void attn_kernel(
    const float* __restrict__ q, const float* __restrict__ k,
    const float* __restrict__ v, float* __restrict__ o, int nqt) {
  __shared__ __bf16 Kt[2][64][128];  // elem col ^ ((row&7)<<3)
  __shared__ __bf16 VT[2][128][64];  // [d][key], key ^ ((d&7)<<3)
  __shared__ __bf16 Pt[4][32][64];   // per-wave, key ^ ((q&7)<<3)

  const int tid = threadIdx.x;
  const int lane = tid & 63;
  const int wid = tid >> 6;
  const int g = lane >> 4, r = lane & 15;
  const int h = blockIdx.x & (NH - 1);
  const int qt = (nqt - 1) - (blockIdx.x >> 4);  // longest blocks first
  const int kvh = h >> 2;
  const int qrow0 = qt * 128 + wid * 32;
  const int limit32 = qt * 4 + wid + 1;  // allowed keys in 32-units
  const int ntb = 2 * qt + 2;            // 64-key tiles staged by the block

  // ---- Q fragments: lane holds Q[qrow0+qh*16+r][32*ks+8*g+j] ----
  bf16x8 qf[2][4];
#pragma unroll
  for (int qh = 0; qh < 2; ++qh)
#pragma unroll
    for (int ks = 0; ks < 4; ++ks) {
      const float* src = q + (size_t)(qrow0 + qh * 16 + r) * QS + h * HD + 32 * ks + 8 * g;
      f32x4 a = *(const f32x4*)src, b = *(const f32x4*)(src + 4);
      bf16x8 t;
      t[0] = (__bf16)a[0]; t[1] = (__bf16)a[1]; t[2] = (__bf16)a[2]; t[3] = (__bf16)a[3];
      t[4] = (__bf16)b[0]; t[5] = (__bf16)b[1]; t[6] = (__bf16)b[2]; t[7] = (__bf16)b[3];
      qf[qh][ks] = t;
    }

  f32x4 oacc[2][8];
#pragma unroll
  for (int qh = 0; qh < 2; ++qh)
#pragma unroll
    for (int nt = 0; nt < 8; ++nt) oacc[qh][nt] = (f32x4){0.f, 0.f, 0.f, 0.f};
  float mrun[2] = {-1e30f, -1e30f}, lrun[2] = {0.f, 0.f};

  // ---- staging (reg-staged, T14 issue-early/write-late) ----
  f32x4 kst[4][2], vst[4][2];

  auto issueK = [&](int kt) {
#pragma unroll
    for (int i = 0; i < 4; ++i) {
      int chunk = tid + i * 256;
      int row = chunk >> 4, col = (chunk & 15) << 3;
      const float* src = k + (size_t)(kt * 64 + row) * KSR + kvh * HD + col;
      kst[i][0] = *(const f32x4*)src;
      kst[i][1] = *(const f32x4*)(src + 4);
    }
  };
  auto issueV = [&](int kt) {
#pragma unroll
    for (int i = 0; i < 4; ++i) {
      int idx = tid + i * 256;
      int kp = idx & 31, dq = idx >> 5;
      const float* s0 = v + (size_t)(kt * 64 + 2 * kp) * KSR + kvh * HD + 4 * dq;
      vst[i][0] = *(const f32x4*)s0;
      vst[i][1] = *(const f32x4*)(s0 + KSR);
    }
  };
  auto writeK = [&](int b) {
#pragma unroll
    for (int i = 0; i < 4; ++i) {
      int chunk = tid + i * 256;
      int row = chunk >> 4, col = (chunk & 15) << 3;
      bf16x8 t;
#pragma unroll
      for (int j = 0; j < 4; ++j) { t[j] = (__bf16)kst[i][0][j]; t[4 + j] = (__bf16)kst[i][1][j]; }
      *(bf16x8*)&Kt[b][row][col ^ ((row & 7) << 3)] = t;
    }
  };
  auto writeV = [&](int b) {
#pragma unroll
    for (int i = 0; i < 4; ++i) {
      int idx = tid + i * 256;
      int kp = idx & 31, dq = idx >> 5;
#pragma unroll
      for (int jj = 0; jj < 4; ++jj) {
        int d = 4 * dq + jj;
        bf16x2 t;
        t[0] = (__bf16)vst[i][0][jj];
        t[1] = (__bf16)vst[i][1][jj];
        *(bf16x2*)&VT[b][d][(2 * kp) ^ ((d & 7) << 3)] = t;
      }
    }
  };

  // ---- compute phases (NG = # of 16-key groups, compile-time) ----
  auto qk_phase = [&](auto NGC, int c) {
    constexpr int NG = decltype(NGC)::value;
    f32x4 sacc[2][NG];
#pragma unroll
    for (int nt2 = 0; nt2 < NG; ++nt2) {
      bf16x8 kf[4];
#pragma unroll
      for (int ks = 0; ks < 4; ++ks)
        kf[ks] = *(const bf16x8*)&Kt[c][16 * nt2 + r][(32 * ks + 8 * g) ^ ((r & 7) << 3)];
#pragma unroll
      for (int qh = 0; qh < 2; ++qh) {
        f32x4 cacc = (f32x4){0.f, 0.f, 0.f, 0.f};
#pragma unroll
        for (int ks = 0; ks < 4; ++ks)
          cacc = __builtin_amdgcn_mfma_f32_16x16x32_bf16(kf[ks], qf[qh][ks], cacc, 0, 0, 0);
        sacc[qh][nt2] = cacc;  // S^T: lane holds S[key=16*nt2+4*g+j][q=r]
      }
    }
#pragma unroll
    for (int qh = 0; qh < 2; ++qh) {
      float mx = -1e30f;
#pragma unroll
      for (int nt2 = 0; nt2 < NG; ++nt2)
#pragma unroll
        for (int j = 0; j < 4; ++j) {
          float s = sacc[qh][nt2][j] * SCALE;
          sacc[qh][nt2][j] = s;
          mx = fmaxf(mx, s);
        }
      mx = fmaxf(mx, __shfl_xor(mx, 16));
      mx = fmaxf(mx, __shfl_xor(mx, 32));
      float mold = mrun[qh];
      float mnew = fmaxf(mold, mx);
      unsigned long long chg = __ballot(mx > mold);
      mrun[qh] = mnew;
      float ts = 0.f;
#pragma unroll
      for (int nt2 = 0; nt2 < NG; ++nt2) {
        bf16x4 pw;
#pragma unroll
        for (int j = 0; j < 4; ++j) {
          float p = __expf(sacc[qh][nt2][j] - mnew);
          ts += p;
          pw[j] = (__bf16)p;
        }
        *(bf16x4*)&Pt[wid][qh * 16 + r][(16 * nt2 + 4 * g) ^ ((r & 7) << 3)] = pw;
      }
      ts += __shfl_xor(ts, 16);
      ts += __shfl_xor(ts, 32);
      if (chg) {  // max grew for some row: exact rescale (exp(0)=1 skip otherwise)
        float cf = __expf(mold - mnew);
        lrun[qh] = lrun[qh] * cf + ts;
#pragma unroll
        for (int j = 0; j < 4; ++j) {
          float cfj = __shfl(cf, 20 * g + j);  // lane with r == 4*g+j
#pragma unroll
          for (int nt = 0; nt < 8; ++nt) oacc[qh][nt][j] *= cfj;
        }
      } else {
        lrun[qh] += ts;
      }
    }
  };

  auto pv_phase = [&](auto NGC, int c) {
    constexpr int NG = decltype(NGC)::value;
    bf16x8 pa[2][NG / 2];
#pragma unroll
    for (int qh = 0; qh < 2; ++qh)
#pragma unroll
      for (int kc = 0; kc < NG / 2; ++kc)
        pa[qh][kc] = *(const bf16x8*)&Pt[wid][qh * 16 + r][(32 * kc + 8 * g) ^ ((r & 7) << 3)];
#pragma unroll
    for (int nt = 0; nt < 8; ++nt) {
#pragma unroll
      for (int kc = 0; kc < NG / 2; ++kc) {
        bf16x8 vf = *(const bf16x8*)&VT[c][16 * nt + r][(32 * kc + 8 * g) ^ ((r & 7) << 3)];
#pragma unroll
        for (int qh = 0; qh < 2; ++qh)
          oacc[qh][nt] = __builtin_amdgcn_mfma_f32_16x16x32_bf16(pa[qh][kc], vf, oacc[qh][nt], 0, 0, 0);
      }
    }
  };

  // ---- prologue: stage tile 0 ----
  issueK(0);
  issueV(0);
  writeK(0);
  writeV(0);
  __syncthreads();

  // ---- main loop: one barrier per 64-key tile ----
  for (int kt = 0; kt < ntb; ++kt) {
    const int c = kt & 1;
    const bool more = (kt + 1 < ntb);
    if (more) { issueK(kt + 1); issueV(kt + 1); }
    const int rem = limit32 - 2 * kt;
    if (rem >= 2)      qk_phase(std::integral_constant<int, 4>{}, c);
    else if (rem == 1) qk_phase(std::integral_constant<int, 2>{}, c);
    if (more) writeK(c ^ 1);  // frees kst regs before PV
    if (rem >= 2)      pv_phase(std::integral_constant<int, 4>{}, c);
    else if (rem == 1) pv_phase(std::integral_constant<int, 2>{}, c);
    if (more) writeV(c ^ 1);
    __syncthreads();
  }

  // ---- epilogue ----
#pragma unroll
  for (int qh = 0; qh < 2; ++qh) {
    float invl = 1.0f / lrun[qh];
#pragma unroll
    for (int j = 0; j < 4; ++j) {
      float iv = __shfl(invl, 20 * g + j);
      int row = qrow0 + qh * 16 + 4 * g + j;
#pragma unroll
      for (int nt = 0; nt < 8; ++nt)
        o[(size_t)row * QS + h * HD + 16 * nt + r] = oacc[qh][nt][j] * iv;
    }
  }
}

// ---------------------------------------------------------------------------
// Cache copy then scatter (ordered on stream)
// ---------------------------------------------------------------------------
__global__ void copy_caches_kernel(const f32x4* __restrict__ kc, const f32x4* __restrict__ vc,
                                   f32x4* __restrict__ okc, f32x4* __restrict__ ovc, int n4) {
  int i = blockIdx.x * blockDim.x + threadIdx.x;
  int stride = gridDim.x * blockDim.x;
  for (; i < n4; i += stride) {
    okc[i] = kc[i];
    ovc[i] = vc[i];
  }
}

__global__ void scatter_kernel(const float* __restrict__ k, const float* __restrict__ v,
                               const int* __restrict__ slot, float* __restrict__ okc,
                               float* __restrict__ ovc, int t) {
  int i = blockIdx.x * blockDim.x + threadIdx.x;
  int row = i >> 7, c = i & 127;
  if (row < t) {
    int s = slot[row];
    ((f32x4*)okc)[(size_t)s * 128 + c] = ((const f32x4*)k)[(size_t)row * 128 + c];
    ((f32x4*)ovc)[(size_t)s * 128 + c] = ((const f32x4*)v)[(size_t)row * 128 + c];
  }
}

extern "C" void kernel_launch(void* const* d_in, const int* in_sizes, int n_in,
                              void* d_out, int out_size, void* d_ws, size_t ws_size,
                              hipStream_t stream) {
  const float* q = (const float*)d_in[0];
  const float* k = (const float*)d_in[1];
  const float* v = (const float*)d_in[2];
  const float* kc = (const float*)d_in[3];
  const float* vc = (const float*)d_in[4];
  const int* slot = (const int*)d_in[5];

  const int t = in_sizes[0] / QS;        // 4096
  const int nslots = in_sizes[3] / KSR;  // 8192
  const int nqt = t / 128;               // 32

  float* o = (float*)d_out;
  float* okc = o + (size_t)t * QS;
  float* ovc = okc + (size_t)nslots * KSR;

  hipLaunchKernelGGL(attn_kernel, dim3(nqt * NH), dim3(256), 0, stream, q, k, v, o, nqt);

  int n4 = nslots * KSR / 4;
  hipLaunchKernelGGL(copy_caches_kernel, dim3(2048), dim3(256), 0, stream,
                     (const f32x4*)kc, (const f32x4*)vc, (f32x4*)okc, (f32x4*)ovc, n4);

  int nthreads = t * (KSR / 4);
  hipLaunchKernelGGL(scatter_kernel, dim3((nthreads + 255) / 256), dim3(256), 0, stream,
                     k, v, slot, okc, ovc, t);
}

// Round 3
// 259.617 us; speedup vs baseline: 4.7977x; 1.4945x over previous
//
#include <hip/hip_runtime.h>
#include <stdint.h>
#include <type_traits>

#define NH 16
#define NKV 4
#define HD 128
#define QS (NH*HD)     /* 2048 */
#define KSR (NKV*HD)   /* 512  */
#define SCALE 0.08838834764831845f
#define CT 32          /* tiles per chunk (split mode) */

typedef float f32x4 __attribute__((ext_vector_type(4)));
typedef __bf16 bf16x8 __attribute__((ext_vector_type(8)));
typedef __bf16 bf16x4 __attribute__((ext_vector_type(4)));

__device__ __forceinline__ void gll16(const void* g, void* l) {
  __builtin_amdgcn_global_load_lds((const __attribute__((address_space(1))) void*)g,
                                   (__attribute__((address_space(3))) void*)l, 16, 0, 0);
}

// ---------------------------------------------------------------------------
// Prepass: K -> bf16 * SCALE, swizzled LDS-image layout [tile][row][col^swz];
//          V -> bf16 transposed image [tile][d][key^swz]. 8192 elems/image.
// ---------------------------------------------------------------------------
__global__ __launch_bounds__(256) void prepass_kernel(
    const float* __restrict__ k, const float* __restrict__ v,
    __bf16* __restrict__ kb, __bf16* __restrict__ vb) {
  const int tid = threadIdx.x;
  const int kvh = blockIdx.x >> 6;
  const int kt = blockIdx.x & 63;
  const size_t ibase = (size_t)(kvh * 64 + kt) << 13;
#pragma unroll
  for (int rep = 0; rep < 8; ++rep) {
    int i = tid + rep * 256;
    int row = i >> 5;         // key within tile
    int c4 = (i & 31) << 2;   // dim base
    f32x4 a = *(const f32x4*)(k + (size_t)(kt * 64 + row) * KSR + kvh * HD + c4);
    bf16x4 t;
    t[0] = (__bf16)(a[0] * SCALE); t[1] = (__bf16)(a[1] * SCALE);
    t[2] = (__bf16)(a[2] * SCALE); t[3] = (__bf16)(a[3] * SCALE);
    *(bf16x4*)&kb[ibase + row * 128 + (c4 ^ ((row & 7) << 3))] = t;
    f32x4 b = *(const f32x4*)(v + (size_t)(kt * 64 + row) * KSR + kvh * HD + c4);
#pragma unroll
    for (int e = 0; e < 4; ++e) {
      int d = c4 + e;
      vb[ibase + d * 64 + (row ^ ((d & 7) << 3))] = (__bf16)b[e];
    }
  }
}

// ---------------------------------------------------------------------------
// Attention. Block = (head, q-tile of 128 rows, key-chunk). 4 waves x 32 rows.
// KVBLK=64, double-buffered LDS filled by global_load_lds from the prepass
// images; counted vmcnt + raw s_barrier keep prefetch in flight (T3/T4).
// qt>=16 (split mode): 2 chunks -> bf16 partials + (m,l), merged by merge_kernel.
// ---------------------------------------------------------------------------
__global__ __launch_bounds__(256, 2) void attn_kernel(
    const float* __restrict__ q, const __bf16* __restrict__ kb,
    const __bf16* __restrict__ vb, float* __restrict__ o,
    __bf16* __restrict__ opart, float2* __restrict__ stats, int mode) {
  __shared__ __bf16 Kt[2][64][128];
  __shared__ __bf16 VT[2][128][64];
  __shared__ __bf16 Pt[4][32][64];

  const int tid = threadIdx.x;
  const int lane = tid & 63;
  const int wid = tid >> 6;
  const int g = lane >> 4, r = lane & 15;
  const int h = blockIdx.x & 15;
  const int u = blockIdx.x >> 4;

  int qt, c;
  if (mode) { qt = 31 - u; c = 0; }
  else if (u < 16) { qt = 31 - u; c = 0; }
  else { qt = 47 - u; c = (u < 32) ? 1 : 0; }

  const int kvh = h >> 2;
  const int nch = (!mode && qt >= 16) ? 2 : 1;
  const int t0 = c * CT;
  const int maxt = mode ? 64 : CT;
  int ntb = 2 * qt + 2 - t0;
  if (ntb > maxt) ntb = maxt;
  const int qrow0 = qt * 128 + wid * 32;
  const int limit32 = qt * 4 + wid + 1;

  // ---- Q fragments ----
  bf16x8 qf[2][4];
#pragma unroll
  for (int qh = 0; qh < 2; ++qh)
#pragma unroll
    for (int ks = 0; ks < 4; ++ks) {
      const float* src = q + (size_t)(qrow0 + qh * 16 + r) * QS + h * HD + 32 * ks + 8 * g;
      f32x4 a = *(const f32x4*)src, b = *(const f32x4*)(src + 4);
      bf16x8 tt;
      tt[0] = (__bf16)a[0]; tt[1] = (__bf16)a[1]; tt[2] = (__bf16)a[2]; tt[3] = (__bf16)a[3];
      tt[4] = (__bf16)b[0]; tt[5] = (__bf16)b[1]; tt[6] = (__bf16)b[2]; tt[7] = (__bf16)b[3];
      qf[qh][ks] = tt;
    }

  f32x4 oacc[2][8];
#pragma unroll
  for (int qh = 0; qh < 2; ++qh)
#pragma unroll
    for (int nt = 0; nt < 8; ++nt) oacc[qh][nt] = (f32x4){0.f, 0.f, 0.f, 0.f};
  float mrun[2] = {-1e30f, -1e30f}, lrun[2] = {0.f, 0.f};

  auto stage = [&](int ktg, int buf) {
    const __bf16* gK = kb + (((size_t)(kvh * 64 + ktg)) << 13) + tid * 8;
    const __bf16* gV = vb + (((size_t)(kvh * 64 + ktg)) << 13) + tid * 8;
    __bf16* lK = &Kt[buf][0][0] + tid * 8;
    __bf16* lV = &VT[buf][0][0] + tid * 8;
#pragma unroll
    for (int i = 0; i < 4; ++i) {
      gll16(gK + i * 2048, lK + i * 2048);
      gll16(gV + i * 2048, lV + i * 2048);
    }
  };

  auto qk_phase = [&](auto NGC, int buf) {
    constexpr int NG = decltype(NGC)::value;
    f32x4 sacc[2][NG];
#pragma unroll
    for (int nt2 = 0; nt2 < NG; ++nt2) {
      bf16x8 kf[4];
#pragma unroll
      for (int ks = 0; ks < 4; ++ks)
        kf[ks] = *(const bf16x8*)&Kt[buf][16 * nt2 + r][(32 * ks + 8 * g) ^ ((r & 7) << 3)];
      __builtin_amdgcn_s_setprio(1);
#pragma unroll
      for (int qh = 0; qh < 2; ++qh) {
        f32x4 cacc = (f32x4){0.f, 0.f, 0.f, 0.f};
#pragma unroll
        for (int ks = 0; ks < 4; ++ks)
          cacc = __builtin_amdgcn_mfma_f32_16x16x32_bf16(kf[ks], qf[qh][ks], cacc, 0, 0, 0);
        sacc[qh][nt2] = cacc;  // S^T: lane holds S[key=16nt2+4g+j][q=r] (pre-scaled)
      }
      __builtin_amdgcn_s_setprio(0);
    }
#pragma unroll
    for (int qh = 0; qh < 2; ++qh) {
      float mx = -1e30f;
#pragma unroll
      for (int nt2 = 0; nt2 < NG; ++nt2)
#pragma unroll
        for (int j = 0; j < 4; ++j) mx = fmaxf(mx, sacc[qh][nt2][j]);
      mx = fmaxf(mx, __shfl_xor(mx, 16));
      mx = fmaxf(mx, __shfl_xor(mx, 32));
      float mold = mrun[qh];
      float mnew = fmaxf(mold, mx);
      unsigned long long chg = __ballot(mx > mold);
      mrun[qh] = mnew;
      float ts = 0.f;
#pragma unroll
      for (int nt2 = 0; nt2 < NG; ++nt2) {
        bf16x4 pw;
#pragma unroll
        for (int j = 0; j < 4; ++j) {
          float p = __expf(sacc[qh][nt2][j] - mnew);
          ts += p;
          pw[j] = (__bf16)p;
        }
        *(bf16x4*)&Pt[wid][qh * 16 + r][(16 * nt2 + 4 * g) ^ ((r & 7) << 3)] = pw;
      }
      ts += __shfl_xor(ts, 16);
      ts += __shfl_xor(ts, 32);
      if (chg) {
        float cf = __expf(mold - mnew);
        lrun[qh] = lrun[qh] * cf + ts;
#pragma unroll
        for (int j = 0; j < 4; ++j) {
          float cfj = __shfl(cf, 20 * g + j);
#pragma unroll
          for (int nt = 0; nt < 8; ++nt) oacc[qh][nt][j] *= cfj;
        }
      } else {
        lrun[qh] += ts;
      }
    }
  };

  auto pv_phase = [&](auto NGC, int buf) {
    constexpr int NG = decltype(NGC)::value;
    bf16x8 pa[2][NG / 2];
#pragma unroll
    for (int qh = 0; qh < 2; ++qh)
#pragma unroll
      for (int kc = 0; kc < NG / 2; ++kc)
        pa[qh][kc] = *(const bf16x8*)&Pt[wid][qh * 16 + r][(32 * kc + 8 * g) ^ ((r & 7) << 3)];
    __builtin_amdgcn_s_setprio(1);
#pragma unroll
    for (int nt = 0; nt < 8; ++nt) {
#pragma unroll
      for (int kc = 0; kc < NG / 2; ++kc) {
        bf16x8 vf = *(const bf16x8*)&VT[buf][16 * nt + r][(32 * kc + 8 * g) ^ ((r & 7) << 3)];
#pragma unroll
        for (int qh = 0; qh < 2; ++qh)
          oacc[qh][nt] = __builtin_amdgcn_mfma_f32_16x16x32_bf16(pa[qh][kc], vf, oacc[qh][nt], 0, 0, 0);
      }
    }
    __builtin_amdgcn_s_setprio(0);
  };

  // ---- prologue ----
  stage(t0, 0);

  for (int j = 0; j < ntb; ++j) {
    const int buf = j & 1;
    if (j + 1 < ntb) {
      stage(t0 + j + 1, buf ^ 1);
      asm volatile("s_waitcnt vmcnt(8)" ::: "memory");
    } else {
      asm volatile("s_waitcnt vmcnt(0)" ::: "memory");
    }
    __builtin_amdgcn_s_barrier();
    __builtin_amdgcn_sched_barrier(0);
    const int rem = limit32 - 2 * (t0 + j);
    if (rem >= 2) {
      qk_phase(std::integral_constant<int, 4>{}, buf);
      pv_phase(std::integral_constant<int, 4>{}, buf);
    } else if (rem == 1) {
      qk_phase(std::integral_constant<int, 2>{}, buf);
      pv_phase(std::integral_constant<int, 2>{}, buf);
    }
    __builtin_amdgcn_sched_barrier(0);
    __builtin_amdgcn_s_barrier();
    __builtin_amdgcn_sched_barrier(0);
  }

  // ---- epilogue ----
  if (nch == 1) {
#pragma unroll
    for (int qh = 0; qh < 2; ++qh) {
      float invl = 1.0f / lrun[qh];
#pragma unroll
      for (int j = 0; j < 4; ++j) {
        float iv = __shfl(invl, 20 * g + j);
        int row = qrow0 + qh * 16 + 4 * g + j;
#pragma unroll
        for (int nt = 0; nt < 8; ++nt)
          o[(size_t)row * QS + h * HD + 16 * nt + r] = oacc[qh][nt][j] * iv;
      }
    }
  } else {
    const int slot = (h * 16 + (qt - 16)) * 2 + c;
    __bf16* op = opart + (size_t)slot * 16384;
#pragma unroll
    for (int qh = 0; qh < 2; ++qh) {
#pragma unroll
      for (int j = 0; j < 4; ++j) {
        int rl = wid * 32 + qh * 16 + 4 * g + j;
#pragma unroll
        for (int nt = 0; nt < 8; ++nt)
          op[rl * 128 + 16 * nt + r] = (__bf16)oacc[qh][nt][j];
      }
      if (g == 0)
        stats[slot * 128 + wid * 32 + qh * 16 + r] = make_float2(mrun[qh], lrun[qh]);
    }
  }
}

// ---------------------------------------------------------------------------
// Merge two chunk-partials per row (qt >= 16 only)
// ---------------------------------------------------------------------------
__global__ __launch_bounds__(256) void merge_kernel(
    const __bf16* __restrict__ opart, const float2* __restrict__ stats,
    float* __restrict__ o) {
  const int bi = blockIdx.x;   // 2048
  const int qtr = bi >> 7;
  const int rm = bi & 127;
  const int h = rm >> 3;
  const int rb = rm & 7;
  const int t = threadIdx.x;
  const int rl = rb * 16 + (t >> 4);
  const int d8 = (t & 15) << 3;
  const int slot = (h * 16 + qtr) * 2;
  float2 s0 = stats[slot * 128 + rl];
  float2 s1 = stats[(slot + 1) * 128 + rl];
  float M = fmaxf(s0.x, s1.x);
  float w0 = __expf(s0.x - M), w1 = __expf(s1.x - M);
  float inv = 1.0f / (s0.y * w0 + s1.y * w1);
  bf16x8 a = *(const bf16x8*)&opart[(size_t)slot * 16384 + rl * 128 + d8];
  bf16x8 b = *(const bf16x8*)&opart[(size_t)(slot + 1) * 16384 + rl * 128 + d8];
  float* dst = o + (size_t)((16 + qtr) * 128 + rl) * QS + h * HD + d8;
  f32x4 o0, o1;
#pragma unroll
  for (int e = 0; e < 4; ++e) o0[e] = ((float)a[e] * w0 + (float)b[e] * w1) * inv;
#pragma unroll
  for (int e = 0; e < 4; ++e) o1[e] = ((float)a[4 + e] * w0 + (float)b[4 + e] * w1) * inv;
  *(f32x4*)dst = o0;
  *(f32x4*)(dst + 4) = o1;
}

// ---------------------------------------------------------------------------
// Cache copy then scatter
// ---------------------------------------------------------------------------
__global__ void copy_caches_kernel(const f32x4* __restrict__ kc, const f32x4* __restrict__ vc,
                                   f32x4* __restrict__ okc, f32x4* __restrict__ ovc, int n4) {
  int i = blockIdx.x * blockDim.x + threadIdx.x;
  int stride = gridDim.x * blockDim.x;
  for (; i < n4; i += stride) {
    okc[i] = kc[i];
    ovc[i] = vc[i];
  }
}

__global__ void scatter_kernel(const float* __restrict__ k, const float* __restrict__ v,
                               const int* __restrict__ slot, float* __restrict__ okc,
                               float* __restrict__ ovc, int t) {
  int i = blockIdx.x * blockDim.x + threadIdx.x;
  int row = i >> 7, c = i & 127;
  if (row < t) {
    int s = slot[row];
    ((f32x4*)okc)[(size_t)s * 128 + c] = ((const f32x4*)k)[(size_t)row * 128 + c];
    ((f32x4*)ovc)[(size_t)s * 128 + c] = ((const f32x4*)v)[(size_t)row * 128 + c];
  }
}

extern "C" void kernel_launch(void* const* d_in, const int* in_sizes, int n_in,
                              void* d_out, int out_size, void* d_ws, size_t ws_size,
                              hipStream_t stream) {
  const float* q = (const float*)d_in[0];
  const float* k = (const float*)d_in[1];
  const float* v = (const float*)d_in[2];
  const float* kc = (const float*)d_in[3];
  const float* vc = (const float*)d_in[4];
  const int* slot = (const int*)d_in[5];

  const int t = in_sizes[0] / QS;        // 4096
  const int nslots = in_sizes[3] / KSR;  // 8192

  float* o = (float*)d_out;
  float* okc = o + (size_t)t * QS;
  float* ovc = okc + (size_t)nslots * KSR;

  __bf16* kb = (__bf16*)d_ws;
  __bf16* vb = kb + 2097152;
  const size_t off_op = (size_t)8 << 20;
  const size_t off_st = off_op + (size_t)512 * 16384 * 2;
  const size_t need_split = off_st + (size_t)512 * 128 * 8;
  __bf16* opart = (__bf16*)((char*)d_ws + off_op);
  float2* stats = (float2*)((char*)d_ws + off_st);

  const int mode = (ws_size >= need_split) ? 0 : 1;

  hipLaunchKernelGGL(prepass_kernel, dim3(256), dim3(256), 0, stream, k, v, kb, vb);
  hipLaunchKernelGGL(attn_kernel, dim3((mode ? 32 : 48) * 16), dim3(256), 0, stream,
                     q, kb, vb, o, opart, stats, mode);
  if (mode == 0)
    hipLaunchKernelGGL(merge_kernel, dim3(2048), dim3(256), 0, stream, opart, stats, o);

  int n4 = nslots * KSR / 4;
  hipLaunchKernelGGL(copy_caches_kernel, dim3(4096), dim3(256), 0, stream,
                     (const f32x4*)kc, (const f32x4*)vc, (f32x4*)okc, (f32x4*)ovc, n4);
  int nthreads = t * (KSR / 4);
  hipLaunchKernelGGL(scatter_kernel, dim3((nthreads + 255) / 256), dim3(256), 0, stream,
                     k, v, slot, okc, ovc, t);
}